// Round 13
// baseline (132.979 us; speedup 1.0000x reference)
//
#include <hip/hip_runtime.h>
#include <math.h>

#define BB 512       // batch rows (M)
#define DD 512       // depth (K)
#define CC 100000    // classes (N)
#define MARGIN2 0.5f
#define PI_F 3.14159265358979323846f

#define BM 64
#define BN 128
#define BK 64
#define KSTEPS (DD / BK)     // 8
#define NPAN 782             // ceil(100000/128), last panel 32 cols
#define GRID (8 * NPAN)      // 6256 = 8 * 782 exactly

typedef __bf16 bf16x8 __attribute__((ext_vector_type(8)));
typedef float f32x4 __attribute__((ext_vector_type(4)));

static __device__ __forceinline__ unsigned short f2bf(float f) {
    union { float f; unsigned u; } v; v.f = f;
    unsigned r = v.u + 0x7FFFu + ((v.u >> 16) & 1u);   // round-to-nearest-even
    return (unsigned short)(r >> 16);
}

// swizzled LDS byte offset for row-major [row][64 x bf16] tiles (row stride 128B)
static __device__ __forceinline__ int swz(int row, int kbyte) {
    return row * 128 + (kbyte ^ ((row & 7) << 4));
}

// async global->LDS, 16B per lane; LDS dest = wave-uniform base + lane*16 (HW rule)
static __device__ __forceinline__ void gll16(const unsigned char* g, unsigned char* l) {
    __builtin_amdgcn_global_load_lds(
        (const __attribute__((address_space(1))) void*)g,
        (__attribute__((address_space(3))) void*)l, 16, 0, 0);
}

// ---------------- K1: row-normalize x -> bf16, PRE-SWIZZLED A images ----------------
// Image layout for BM=64: img[(mb*8 + t)*8192 + swz(lrow, c8*16) + sub*8],
// mb = row>>6 (0..7), lrow = row&63 -> gemm's linear global_load_lds reproduces
// the swizzled A-tile layout exactly (m173 pattern).
__global__ __launch_bounds__(256) void k_norm_x(const float* __restrict__ x,
                                                unsigned char* __restrict__ img) {
    const int lane = threadIdx.x & 63;
    const int row  = blockIdx.x * 4 + (threadIdx.x >> 6);
    const float* xr = x + (size_t)row * DD;
    float4 v0 = *(const float4*)(xr + lane * 4);
    float4 v1 = *(const float4*)(xr + lane * 4 + 256);
    float s = v0.x*v0.x + v0.y*v0.y + v0.z*v0.z + v0.w*v0.w
            + v1.x*v1.x + v1.y*v1.y + v1.z*v1.z + v1.w*v1.w;
    #pragma unroll
    for (int m = 32; m; m >>= 1) s += __shfl_xor(s, m, 64);
    float rs = rsqrtf(fmaxf(s, 1e-12f));
    ushort4 o0, o1;
    o0.x = f2bf(v0.x * rs); o0.y = f2bf(v0.y * rs);
    o0.z = f2bf(v0.z * rs); o0.w = f2bf(v0.w * rs);
    o1.x = f2bf(v1.x * rs); o1.y = f2bf(v1.y * rs);
    o1.z = f2bf(v1.z * rs); o1.w = f2bf(v1.w * rs);

    const int mb   = row >> 6;            // which 64-row M block (0..7)
    const int lrow = row & 63;
    const int k0   = lane * 4;            // v0 covers k0..k0+3; v1 covers k0+256..
    const int t0   = k0 >> 6;             // 0..3 (v1 -> t0+4)
    const int c8   = (k0 >> 3) & 7;       // 16B chunk within 128B row
    const int sub  = (k0 >> 2) & 1;       // 8B half of the chunk
    const int base = (mb * 8 + t0) * 8192 + lrow * 128
                   + ((c8 * 16) ^ ((lrow & 7) << 4)) + sub * 8;
    *(ushort4*)(img + base)         = o0;
    *(ushort4*)(img + base + 32768) = o1;    // t0+4 image (4 * 8192)
}

// ---------------- K2: bf16 MFMA GEMM, 64x128 tile, 6 waves/SIMD pipeline ----
// 512 threads / 8 waves of 32x32 (acc = 4 frags = 16 AGPR). Single B-reg set
// (pack then reload same regs; scoreboard WAR) -> combined regs ~70 <= 85 ->
// launch_bounds(512,6) = 6 waves/SIMD; LDS 48.5KB -> 3 blocks/CU = 24 waves/CU.
// R12 pipeline: [gll A(t+1):1][MFMA t, setprio][PACK+write B(t+1), auto vmcnt(1)]
// [LOAD B(t+2):16][vmcnt(16) drains gll only][lgkmcnt(0)][s_barrier].
// B(t+2) rides through the barrier (T4); max 17 in flight.
#define ABUF 8192
#define LDSZ (2 * ABUF + 2 * 16384 + 512)   // 49664 -> 3 blocks/CU

__global__ __launch_bounds__(512, 6) void k_gemm(const unsigned char* __restrict__ img,
                                                 const float* __restrict__ W,
                                                 float* __restrict__ out) {
    __shared__ __align__(16) unsigned char LDS[LDSZ];
    unsigned char* bufA = LDS;                  // 2 x 8KB
    unsigned char* bufB = LDS + 2 * ABUF;       // 2 x 16KB
    float* rn = (float*)(LDS + 2 * ABUF + 32768);

    const int tid = threadIdx.x;
    const int bid = blockIdx.x;

    // bijective XCD swizzle: 6256 = 8*782; the 8 mb-sharers of a W panel are
    // consecutive v on the same XCD -> panel (256KB) hits that XCD's L2.
    const int v  = (bid & 7) * 782 + (bid >> 3);
    const int mb = v & 7;
    const int nb = v >> 3;
    const int M0 = mb * BM;
    const int N0 = nb * BN;

    const int lane = tid & 63;
    const int wid  = tid >> 6;     // 0..7
    const int wm = wid >> 2;       // 0..1 -> 32 rows each
    const int wn = wid & 3;        // 0..3 -> 32 cols each
    const int lr = lane & 15;
    const int lg = lane >> 4;

    // ---- B staging tasks: 4 per thread; s = kq*128 + n (bijective, also part[] slot) ----
    int b_go[4], b_ld[4];
    #pragma unroll
    for (int i = 0; i < 4; ++i) {
        int s  = tid + i * 512;
        int n  = s & 127;
        int kq = s >> 7;                       // 0..15, quad of k
        int col = N0 + n;
        col = col < CC ? col : CC - 1;         // tail-panel clamp (dead cols)
        b_go[i] = kq * 4 * CC + col;
        b_ld[i] = n * 128 + ((kq * 8) ^ ((n & 7) << 4));
    }

    const unsigned char* imgA = img + mb * (8 * ABUF);
    const int lds_u = wid * 1024;              // wave-uniform part of linear offset

    float f[4][4];                             // single B-reg set (depth-2 via WAR reuse)
    float bsq[4] = {0.f, 0.f, 0.f, 0.f};

#define WAITV_(N) asm volatile("s_waitcnt vmcnt(" #N ")" ::: "memory")
#define WAITV(N) WAITV_(N)
#define SB() __builtin_amdgcn_sched_barrier(0)

#define LOAD_B(T) do {                                                         \
    _Pragma("unroll")                                                          \
    for (int i = 0; i < 4; ++i) {                                              \
        const float* p = W + b_go[i] + (size_t)(T) * (BK * CC);                \
        f[i][0] = p[0];      f[i][1] = p[CC];                                  \
        f[i][2] = p[2 * CC]; f[i][3] = p[3 * CC];                              \
    } } while (0)

// pack + write immediately; frees f[] for the next LOAD_B (WAR via scoreboard)
#define PACK_WRITE(T) do {                                                     \
    unsigned char* dst = bufB + ((T) & 1) * 16384;                             \
    _Pragma("unroll")                                                          \
    for (int i = 0; i < 4; ++i) {                                              \
        bsq[i] += f[i][0] * f[i][0] + f[i][1] * f[i][1]                        \
                + f[i][2] * f[i][2] + f[i][3] * f[i][3];                       \
        unsigned w0, w1;                                                       \
        asm("v_cvt_pk_bf16_f32 %0, %1, %2" : "=v"(w0) : "v"(f[i][0]), "v"(f[i][1])); \
        asm("v_cvt_pk_bf16_f32 %0, %1, %2" : "=v"(w1) : "v"(f[i][2]), "v"(f[i][3])); \
        uint2 w; w.x = w0; w.y = w1;                                           \
        *(uint2*)(dst + b_ld[i]) = w;                                          \
    } } while (0)

#define GLL_A(T) do {                                                          \
    unsigned char* A_nxt = bufA + ((T) & 1) * ABUF;                            \
    const unsigned char* gsrc = imgA + (T) * ABUF;                             \
    gll16(gsrc + lds_u + lane * 16, A_nxt + lds_u);                            \
    } while (0)

#define COMPUTE(T) do {                                                        \
    const unsigned char* A_cur = bufA + ((T) & 1) * ABUF;                      \
    const unsigned char* B_cur = bufB + ((T) & 1) * 16384;                     \
    __builtin_amdgcn_s_setprio(1);                                             \
    _Pragma("unroll")                                                          \
    for (int ks = 0; ks < 2; ++ks) {                                           \
        bf16x8 af[2], bfr[2];                                                  \
        _Pragma("unroll")                                                      \
        for (int mf = 0; mf < 2; ++mf)                                         \
            af[mf] = *(const bf16x8*)(A_cur + swz(wm * 32 + mf * 16 + lr, ks * 64 + lg * 16)); \
        _Pragma("unroll")                                                      \
        for (int nf = 0; nf < 2; ++nf)                                         \
            bfr[nf] = *(const bf16x8*)(B_cur + swz(wn * 32 + nf * 16 + lr, ks * 64 + lg * 16)); \
        _Pragma("unroll")                                                      \
        for (int mf = 0; mf < 2; ++mf)                                         \
            _Pragma("unroll")                                                  \
            for (int nf = 0; nf < 2; ++nf)                                     \
                acc[mf][nf] = __builtin_amdgcn_mfma_f32_16x16x32_bf16(         \
                    bfr[nf], af[mf], acc[mf][nf], 0, 0, 0);                    \
    }                                                                          \
    __builtin_amdgcn_s_setprio(0);                                             \
    } while (0)

#define KBODY(T) do {                                                          \
    if ((T) + 1 < KSTEPS) GLL_A((T) + 1);                                      \
    SB();                                                                      \
    COMPUTE(T);                                                                \
    SB();                                                                      \
    if ((T) + 1 < KSTEPS) PACK_WRITE((T) + 1);   /* auto vmcnt(1): B(T+1) */   \
    if ((T) + 2 < KSTEPS) LOAD_B((T) + 2);       /* reuse f[]; WAR safe */     \
    SB();                                                                      \
    if ((T) + 1 < KSTEPS) {                                                    \
        if ((T) + 2 < KSTEPS) { WAITV(16); } else { WAITV(0); }                \
        SB();                                                                  \
        asm volatile("s_waitcnt lgkmcnt(0)" ::: "memory"); SB();               \
        __builtin_amdgcn_s_barrier(); SB();                                    \
    } } while (0)

    f32x4 acc[2][2];
    #pragma unroll
    for (int mf = 0; mf < 2; ++mf)
        #pragma unroll
        for (int nf = 0; nf < 2; ++nf)
            acc[mf][nf] = (f32x4)0.f;

    // ---- prologue: B(0):16 + gll(0):1; pack B(0) (auto vmcnt(1)); B(1):16; drain gll ----
    LOAD_B(0);
    GLL_A(0);
    SB();
    PACK_WRITE(0);                         // auto wait drains B(0), keeps gll(0)
    LOAD_B(1);                             // outstanding: gll(0):1 + B(1):16 = 17
    SB();
    WAITV(16); SB();                       // drain gll(0); B(1) rides through barrier
    asm volatile("s_waitcnt lgkmcnt(0)" ::: "memory"); SB();
    __builtin_amdgcn_s_barrier(); SB();

    KBODY(0); KBODY(1); KBODY(2); KBODY(3);
    KBODY(4); KBODY(5); KBODY(6); KBODY(7);

    // ---- deterministic column-norm reduction (reuse bufB) ----
    __syncthreads();
    float* part = (float*)bufB;                // [16][128] floats = 8KB
    #pragma unroll
    for (int i = 0; i < 4; ++i)
        part[tid + i * 512] = bsq[i];          // slot = kq*128+n, unique owner
    __syncthreads();
    if (tid < BN) {
        float s = 0.f;
        #pragma unroll
        for (int k = 0; k < 16; ++k)
            s += part[k * BN + tid];           // fixed order -> deterministic
        rn[tid] = rsqrtf(fmaxf(s, 1e-12f));
    }
    __syncthreads();

    // ---- epilogue: LDS-staged -> 512B-aligned full-sector non-temporal stores ----
    float* stag = (float*)bufB;                // 32 rows x 132 floats = 16.9KB
    #pragma unroll
    for (int rd = 0; rd < 2; ++rd) {
        if (wm == rd) {
            #pragma unroll
            for (int mf = 0; mf < 2; ++mf) {
                const int ml = mf * 16 + lr;
                #pragma unroll
                for (int nf = 0; nf < 2; ++nf) {
                    const int nl = wn * 32 + nf * 16 + lg * 4;
                    const f32x4 rn4 = *(const f32x4*)(rn + nl);
                    f32x4 o;
                    #pragma unroll
                    for (int r = 0; r < 4; ++r)
                        o[r] = acc[mf][nf][r] * rn4[r];
                    *(f32x4*)(stag + ml * 132 + nl) = o;
                }
            }
        }
        __syncthreads();
        #pragma unroll
        for (int j = tid; j < 1024; j += 512) {
            const int m = j >> 5;
            const int n = (j & 31) * 4;
            if (N0 + n + 4 <= CC) {
                f32x4 o = *(const f32x4*)(stag + m * 132 + n);
                __builtin_nontemporal_store(o,
                    (f32x4*)(out + (size_t)(M0 + rd * 32 + m) * CC + N0 + n));
            }
        }
        __syncthreads();
    }
}

// ---------------- K3: margin fixup at label positions ----------------
__global__ __launch_bounds__(512) void k_fix(const int* __restrict__ lab,
                                             float* __restrict__ out) {
    const int b = threadIdx.x;
    const int c = lab[b];
    const size_t idx = (size_t)b * CC + c;
    float t = out[idx];
    t = fminf(fmaxf(t, -1.f), 1.f);
    float th = acosf(t) + MARGIN2;
    th = fminf(th, PI_F);              // min(t, t + (pi - stopgrad(t))) value-wise
    out[idx] = cosf(th);               // M3 == 0: no additive term
}

extern "C" void kernel_launch(void* const* d_in, const int* in_sizes, int n_in,
                              void* d_out, int out_size, void* d_ws, size_t ws_size,
                              hipStream_t stream) {
    const float* x   = (const float*)d_in[0];
    const float* W   = (const float*)d_in[1];
    const int*   lab = (const int*)d_in[2];
    float* out = (float*)d_out;

    unsigned char* img = (unsigned char*)d_ws;   // 512KB pre-swizzled xn images

    k_norm_x<<<dim3(BB / 4), dim3(256), 0, stream>>>(x, img);
    k_gemm<<<dim3(GRID), dim3(512), 0, stream>>>(img, W, out);
    k_fix<<<dim3(1), dim3(512), 0, stream>>>(lab, out);
}